// Round 5
// baseline (511.301 us; speedup 1.0000x reference)
//
#include <hip/hip_runtime.h>
#include <math.h>

// Problem constants (fixed by the reference)
#define G    120     // B*T frames
#define Nn   2000    // nodes per frame
#define Ee   32000   // edges per frame
#define Fh   64      // GCN hidden
#define Tt   30
#define Bb   4
#define Fg   128     // GRU hidden
#define QCAP 9216    // CSR capacity per (frame,quadrant); expected 8000, sigma 78

// ---- K1: fused CSR build: histogram + scan + fill in LDS, coalesced write-out.
// One block per (frame g, dst-quadrant q of 500 nodes). Also emits dis=rsqrt(deg)
// and zeroes emb (pool accumulator).
__global__ void __launch_bounds__(1024, 1)
k_csr(const int* __restrict__ ei, float* __restrict__ dis,
      int* __restrict__ startA, int* __restrict__ cntA,
      int* __restrict__ csr, float* __restrict__ emb) {
    __shared__ int hist[500];      // histogram, then cursor
    __shared__ int ws[512];        // scan workspace
    __shared__ int csr_l[QCAP];
    int gq = blockIdx.x;
    int g = gq >> 2, q = gq & 3;
    int lo = q * 500, hi = lo + 500;
    int tid = threadIdx.x;
    if (tid < 500) hist[tid] = 0;
    if (q == 0 && tid < 64) emb[g * 64 + tid] = 0.f;
    __syncthreads();
    const int* srcp = ei + (size_t)g * 2 * Ee;
    const int* dstp = srcp + Ee;
    // phase 1: histogram of in-range destinations
    for (int i = tid; i < Ee / 4; i += 1024) {
        int4 d = reinterpret_cast<const int4*>(dstp)[i];
        if (d.x >= lo && d.x < hi) atomicAdd(&hist[d.x - lo], 1);
        if (d.y >= lo && d.y < hi) atomicAdd(&hist[d.y - lo], 1);
        if (d.z >= lo && d.z < hi) atomicAdd(&hist[d.z - lo], 1);
        if (d.w >= lo && d.w < hi) atomicAdd(&hist[d.w - lo], 1);
    }
    __syncthreads();
    // phase 2: inclusive scan over 512 (500 live) entries
    if (tid < 512) ws[tid] = (tid < 500) ? hist[tid] : 0;
    __syncthreads();
    for (int off = 1; off < 512; off <<= 1) {
        int v = 0;
        if (tid < 512 && tid >= off) v = ws[tid - off];
        __syncthreads();
        if (tid < 512) ws[tid] += v;
        __syncthreads();
    }
    if (tid < 500) {
        int cnt = hist[tid];
        int ex = ws[tid] - cnt;                    // exclusive prefix
        int n = lo + tid;
        startA[(size_t)g * Nn + n] = gq * QCAP + ex;
        cntA[(size_t)g * Nn + n]   = cnt;
        dis[(size_t)g * Nn + n]    = rsqrtf((float)cnt + 1.0f);
        hist[tid] = ex;                            // reuse as cursor
    }
    __syncthreads();
    // phase 3: scatter-fill CSR in LDS
    for (int i = tid; i < Ee / 4; i += 1024) {
        int4 d = reinterpret_cast<const int4*>(dstp)[i];
        int4 s = reinterpret_cast<const int4*>(srcp)[i];
        if (d.x >= lo && d.x < hi) { int p = atomicAdd(&hist[d.x - lo], 1); if (p < QCAP) csr_l[p] = s.x; }
        if (d.y >= lo && d.y < hi) { int p = atomicAdd(&hist[d.y - lo], 1); if (p < QCAP) csr_l[p] = s.y; }
        if (d.z >= lo && d.z < hi) { int p = atomicAdd(&hist[d.z - lo], 1); if (p < QCAP) csr_l[p] = s.z; }
        if (d.w >= lo && d.w < hi) { int p = atomicAdd(&hist[d.w - lo], 1); if (p < QCAP) csr_l[p] = s.w; }
    }
    __syncthreads();
    // phase 4: coalesced write-out
    int total = ws[511];
    int* cg = csr + (size_t)gq * QCAP;
    for (int i = tid; i < total; i += 1024) cg[i] = csr_l[i];
}

// ---- K2: precompute per-edge (src, weight) with full sym-norm folded in.
// One thread per destination node; walks its CSR range.
__global__ void k_wgt(const float* __restrict__ dis, const int* __restrict__ startA,
                      const int* __restrict__ cntA, const int* __restrict__ csr,
                      int2* __restrict__ ew) {
    int i = blockIdx.x * 256 + threadIdx.x;
    if (i >= G * Nn) return;
    int g = i / Nn;
    const float* ds = dis + (size_t)g * Nn;
    float dn = dis[i];
    int o0 = startA[i], cnt = cntA[i];
    for (int j = 0; j < cnt; ++j) {
        int s = csr[o0 + j];
        ew[o0 + j] = make_int2(s, __float_as_int(ds[s] * dn));
    }
}

// ---- K3: aggregate RAW x (8-dim) with precomputed weights
__global__ void k_agg8(const float* __restrict__ x, const float* __restrict__ dis,
                       const int* __restrict__ startA, const int* __restrict__ cntA,
                       const int2* __restrict__ ew, float* __restrict__ aggX) {
    int g = blockIdx.y;
    int n = blockIdx.x * 32 + (threadIdx.x >> 3);
    int f = threadIdx.x & 7;
    if (n >= Nn) return;
    size_t gn = (size_t)g * Nn + n;
    const float* xb = x + (size_t)g * Nn * 8;
    float dn = dis[gn];
    float acc = xb[(size_t)n * 8 + f] * dn * dn;
    float acc2 = 0.f;
    int o0 = startA[gn];
    int o1 = o0 + cntA[gn];
    int e = o0;
    for (; e + 2 <= o1; e += 2) {
        int2 p0 = ew[e], p1 = ew[e + 1];
        acc  += xb[(size_t)p0.x * 8 + f] * __int_as_float(p0.y);
        acc2 += xb[(size_t)p1.x * 8 + f] * __int_as_float(p1.y);
    }
    if (e < o1) {
        int2 p = ew[e];
        acc += xb[(size_t)p.x * 8 + f] * __int_as_float(p.y);
    }
    aggX[gn * 8 + f] = acc + acc2;
}

// ---- K4: fused t2 = relu(aggX@W1 + b1) @ W2, 32 nodes/block, XCD-pinned.
// h1 tile lives in LDS (stride 65 = conflict-free); W2 read as LDS float4.
__global__ void __launch_bounds__(256)
k_mmf(const float* __restrict__ aggX, const float* __restrict__ W1,
      const float* __restrict__ b1, const float* __restrict__ W2,
      float* __restrict__ t2) {
    __shared__ float Ws1[512];
    __shared__ float bs[64];
    __shared__ float xs[256];
    __shared__ float W2s[4096];
    __shared__ float h1s[32 * 65];
    int i = blockIdx.x;            // 0..7559; round-robin over 8 XCDs
    int xcd = i & 7;
    int j = i >> 3;                // 0..944
    int f15 = j / 63;              // 0..14
    int bx = j % 63;
    int g = xcd * 15 + f15;
    int tid = threadIdx.x;
    Ws1[tid]       = W1[tid];
    Ws1[tid + 256] = W1[tid + 256];
    if (tid < 64) bs[tid] = b1[tid];
    { int idx = bx * 256 + tid; xs[tid] = (idx < Nn * 8) ? aggX[(size_t)g * Nn * 8 + idx] : 0.f; }
#pragma unroll
    for (int k2 = 0; k2 < 16; ++k2) W2s[k2 * 256 + tid] = W2[k2 * 256 + tid];
    __syncthreads();
    // phase 1: h1 = relu(aggX@W1 + b1) into LDS
    int f = tid & 63, rr = tid >> 6;
#pragma unroll
    for (int ii = 0; ii < 8; ++ii) {
        int r = rr + 4 * ii;
        float acc = bs[f];
#pragma unroll
        for (int k = 0; k < 8; ++k) acc += xs[r * 8 + k] * Ws1[k * 64 + f];
        h1s[r * 65 + f] = fmaxf(acc, 0.f);
    }
    __syncthreads();
    // phase 2: t2 = h1 @ W2, each thread: 1 node x 8 features
    int r2 = tid >> 3, fg = tid & 7;
    int n = bx * 32 + r2;
    if (n < Nn) {
        float4 a0 = {0.f, 0.f, 0.f, 0.f}, a1 = {0.f, 0.f, 0.f, 0.f};
        const float4* W24 = reinterpret_cast<const float4*>(W2s);
#pragma unroll 8
        for (int k = 0; k < 64; ++k) {
            float xv = h1s[r2 * 65 + k];
            float4 w0 = W24[k * 16 + fg * 2];
            float4 w1 = W24[k * 16 + fg * 2 + 1];
            a0.x += xv * w0.x; a0.y += xv * w0.y; a0.z += xv * w0.z; a0.w += xv * w0.w;
            a1.x += xv * w1.x; a1.y += xv * w1.y; a1.z += xv * w1.z; a1.w += xv * w1.w;
        }
        float4* op = reinterpret_cast<float4*>(t2 + ((size_t)g * Nn + n) * 64 + fg * 8);
        op[0] = a0; op[1] = a1;
    }
}

// ---- K5: h2 = relu(agg(t2)+b2) fused with mean-pool (h2 never materialized).
// XCD-pinned swizzle; 4 nodes/block (one per wave); LDS reduce + 1 atomic wave.
__global__ void k_agg64p(const float* __restrict__ t2, const float* __restrict__ dis,
                         const int* __restrict__ startA, const int* __restrict__ cntA,
                         const int2* __restrict__ ew, const float* __restrict__ bias,
                         float* __restrict__ emb) {
    __shared__ float red[256];
    int i = blockIdx.x;            // 0..59999
    int xcd = i & 7;
    int chunk = i >> 3;            // 0..7499
    int ng = chunk % 500;
    int f15 = chunk / 500;         // 0..14
    int g = xcd * 15 + f15;
    int n = ng * 4 + (threadIdx.x >> 6);
    int f = threadIdx.x & 63;
    size_t gn = (size_t)g * Nn + n;
    const float* base = t2 + (size_t)g * Nn * 64;
    float dn = dis[gn];
    float acc = base[(size_t)n * 64 + f] * dn * dn;        // self-loop norm = 1/deg
    float acc2 = 0.f;
    int o0 = startA[gn];
    int o1 = o0 + cntA[gn];
    int e = o0;
    for (; e + 2 <= o1; e += 2) {
        int2 p0 = ew[e], p1 = ew[e + 1];
        acc  += base[(size_t)p0.x * 64 + f] * __int_as_float(p0.y);
        acc2 += base[(size_t)p1.x * 64 + f] * __int_as_float(p1.y);
    }
    if (e < o1) {
        int2 p = ew[e];
        acc += base[(size_t)p.x * 64 + f] * __int_as_float(p.y);
    }
    float val = fmaxf(acc + acc2 + bias[f], 0.f);
    red[threadIdx.x] = val;
    __syncthreads();
    if (threadIdx.x < 64) {
        float s = red[threadIdx.x] + red[64 + threadIdx.x] +
                  red[128 + threadIdx.x] + red[192 + threadIdx.x];
        atomicAdd(&emb[g * 64 + threadIdx.x], s * (1.0f / Nn));
    }
}

// ---- K6: gi[g][384] = emb[g] @ W_ih^T + b_ih (parallel over frames)
__global__ void k_gi(const float* __restrict__ emb, const float* __restrict__ W_ih,
                     const float* __restrict__ b_ih, float* __restrict__ gi) {
    __shared__ float xs[64];
    int g = blockIdx.x;          // g = b*Tt + t
    int j = threadIdx.x;         // 0..383
    if (j < 64) xs[j] = emb[g * 64 + j];
    __syncthreads();
    float a0 = 0.f, a1 = 0.f, a2 = 0.f, a3 = 0.f;
    const float* wr = W_ih + j * 64;
#pragma unroll
    for (int k = 0; k < 16; ++k) {
        a0 += wr[4 * k + 0] * xs[4 * k + 0];
        a1 += wr[4 * k + 1] * xs[4 * k + 1];
        a2 += wr[4 * k + 2] * xs[4 * k + 2];
        a3 += wr[4 * k + 3] * xs[4 * k + 3];
    }
    gi[(size_t)g * 384 + j] = b_ih[j] + ((a0 + a1) + (a2 + a3));
}

// ---- K7: sequential GRU over T, one block per batch, W_hh in regs + final FC
__global__ void __launch_bounds__(768, 1)
k_gru_seq(const float* __restrict__ gi, const float* __restrict__ W_hh,
          const float* __restrict__ b_hh, const float* __restrict__ fc_w,
          const float* __restrict__ fc_b, float* __restrict__ out) {
    __shared__ float h[Fg];
    __shared__ float part[768];
    int b = blockIdx.x;                  // batch
    int tid = threadIdx.x;               // 0..767
    int row = tid >> 1;                  // gate-row 0..383
    int half = tid & 1;                  // which 64-slice of k
    float w[64];
    const float* wr = W_hh + (size_t)row * Fg + half * 64;
#pragma unroll
    for (int i = 0; i < 64; ++i) w[i] = wr[i];
    if (tid < Fg) h[tid] = 0.f;
    __syncthreads();
    for (int t = 0; t < Tt; ++t) {
        const float* hh = &h[half * 64];
        float a0 = 0.f, a1 = 0.f, a2 = 0.f, a3 = 0.f;
#pragma unroll
        for (int i = 0; i < 16; ++i) {
            a0 += w[4 * i + 0] * hh[4 * i + 0];
            a1 += w[4 * i + 1] * hh[4 * i + 1];
            a2 += w[4 * i + 2] * hh[4 * i + 2];
            a3 += w[4 * i + 3] * hh[4 * i + 3];
        }
        part[tid] = (a0 + a1) + (a2 + a3);
        __syncthreads();
        if (tid < Fg) {
            int j = tid;
            const float* gib = gi + ((size_t)b * Tt + t) * 384;
            float hr = b_hh[j]       + part[2 * j]           + part[2 * j + 1];
            float hz = b_hh[128 + j] + part[2 * (128 + j)]   + part[2 * (128 + j) + 1];
            float hn = b_hh[256 + j] + part[2 * (256 + j)]   + part[2 * (256 + j) + 1];
            float r  = 1.f / (1.f + expf(-(gib[j] + hr)));
            float z  = 1.f / (1.f + expf(-(gib[128 + j] + hz)));
            float nn = tanhf(gib[256 + j] + r * hn);
            h[j] = (1.f - z) * nn + z * h[j];
        }
        __syncthreads();
    }
    if (tid < 2) {
        float acc = fc_b[tid];
        for (int k = 0; k < Fg; ++k) acc += fc_w[tid * Fg + k] * h[k];
        out[b * 2 + tid] = acc;
    }
}

// ----------------------------------------------------------------- launcher
extern "C" void kernel_launch(void* const* d_in, const int* in_sizes, int n_in,
                              void* d_out, int out_size, void* d_ws, size_t ws_size,
                              hipStream_t stream) {
    const float* x     = (const float*)d_in[0];
    const int*   ei    = (const int*)  d_in[1];
    const float* W1    = (const float*)d_in[2];
    const float* b1    = (const float*)d_in[3];
    const float* W2    = (const float*)d_in[4];
    const float* b2    = (const float*)d_in[5];
    const float* W_ih  = (const float*)d_in[6];
    const float* W_hh  = (const float*)d_in[7];
    const float* b_ih  = (const float*)d_in[8];
    const float* b_hh  = (const float*)d_in[9];
    const float* fc_w  = (const float*)d_in[10];
    const float* fc_b  = (const float*)d_in[11];
    float* out = (float*)d_out;

    char* ws = (char*)d_ws;
    size_t off = 0;
    auto alloc = [&](size_t bytes) -> void* {
        void* p = ws + off;
        off = (off + bytes + 255) & ~(size_t)255;
        return p;
    };
    float* dis     = (float*)alloc((size_t)G * Nn * 4);
    int*   startA  = (int*)  alloc((size_t)G * Nn * 4);
    int*   cntA    = (int*)  alloc((size_t)G * Nn * 4);
    int*   csr     = (int*)  alloc((size_t)G * 4 * QCAP * 4);
    int2*  ew      = (int2*) alloc((size_t)G * 4 * QCAP * 8);
    float* aggX    = (float*)alloc((size_t)G * Nn * 8 * 4);
    float* t2      = (float*)alloc((size_t)G * Nn * 64 * 4);
    float* emb     = (float*)alloc((size_t)G * 64 * 4);
    float* gi      = (float*)alloc((size_t)G * 384 * 4);
    (void)ws_size; (void)in_sizes; (void)n_in; (void)out_size;

    hipLaunchKernelGGL(k_csr,    dim3(G * 4), dim3(1024), 0, stream, ei, dis, startA, cntA, csr, emb);
    hipLaunchKernelGGL(k_wgt,    dim3((G * Nn + 255) / 256), dim3(256), 0, stream, dis, startA, cntA, csr, ew);
    hipLaunchKernelGGL(k_agg8,   dim3(63, G), dim3(256), 0, stream, x, dis, startA, cntA, ew, aggX);
    hipLaunchKernelGGL(k_mmf,    dim3(7560), dim3(256), 0, stream, aggX, W1, b1, W2, t2);
    hipLaunchKernelGGL(k_agg64p, dim3(60000), dim3(256), 0, stream, t2, dis, startA, cntA, ew, b2, emb);
    hipLaunchKernelGGL(k_gi,     dim3(G), dim3(384), 0, stream, emb, W_ih, b_ih, gi);
    hipLaunchKernelGGL(k_gru_seq, dim3(Bb), dim3(768), 0, stream, gi, W_hh, b_hh, fc_w, fc_b, out);
}

// Round 6
// 452.794 us; speedup vs baseline: 1.1292x; 1.1292x over previous
//
#include <hip/hip_runtime.h>
#include <math.h>

// Problem constants (fixed by the reference)
#define G    120     // B*T frames
#define Nn   2000    // nodes per frame
#define Ee   32000   // edges per frame
#define Fh   64      // GCN hidden
#define Tt   30
#define Bb   4
#define Fg   128     // GRU hidden
#define QCAP 9216    // CSR capacity per (frame,quadrant); expected 8000, sigma 78
#define PAD  32      // ELL slots/node: slot0=self-loop, 1..31 edges, pad w=0

// ---- K1: fused CSR build: histogram + scan + fill in LDS, coalesced write-out.
// One block per (frame g, dst-quadrant q of 500 nodes). Also emits dis=rsqrt(deg)
// and zeroes emb (pool accumulator).
__global__ void __launch_bounds__(1024, 1)
k_csr(const int* __restrict__ ei, float* __restrict__ dis,
      int* __restrict__ startA, int* __restrict__ cntA,
      int* __restrict__ csr, float* __restrict__ emb) {
    __shared__ int hist[500];      // histogram, then cursor
    __shared__ int ws[512];        // scan workspace
    __shared__ int csr_l[QCAP];
    int gq = blockIdx.x;
    int g = gq >> 2, q = gq & 3;
    int lo = q * 500, hi = lo + 500;
    int tid = threadIdx.x;
    if (tid < 500) hist[tid] = 0;
    if (q == 0 && tid < 64) emb[g * 64 + tid] = 0.f;
    __syncthreads();
    const int* srcp = ei + (size_t)g * 2 * Ee;
    const int* dstp = srcp + Ee;
    // phase 1: histogram of in-range destinations
    for (int i = tid; i < Ee / 4; i += 1024) {
        int4 d = reinterpret_cast<const int4*>(dstp)[i];
        if (d.x >= lo && d.x < hi) atomicAdd(&hist[d.x - lo], 1);
        if (d.y >= lo && d.y < hi) atomicAdd(&hist[d.y - lo], 1);
        if (d.z >= lo && d.z < hi) atomicAdd(&hist[d.z - lo], 1);
        if (d.w >= lo && d.w < hi) atomicAdd(&hist[d.w - lo], 1);
    }
    __syncthreads();
    // phase 2: inclusive scan over 512 (500 live) entries
    if (tid < 512) ws[tid] = (tid < 500) ? hist[tid] : 0;
    __syncthreads();
    for (int off = 1; off < 512; off <<= 1) {
        int v = 0;
        if (tid < 512 && tid >= off) v = ws[tid - off];
        __syncthreads();
        if (tid < 512) ws[tid] += v;
        __syncthreads();
    }
    if (tid < 500) {
        int cnt = hist[tid];
        int ex = ws[tid] - cnt;                    // exclusive prefix
        int n = lo + tid;
        startA[(size_t)g * Nn + n] = gq * QCAP + ex;
        cntA[(size_t)g * Nn + n]   = cnt;
        dis[(size_t)g * Nn + n]    = rsqrtf((float)cnt + 1.0f);
        hist[tid] = ex;                            // reuse as cursor
    }
    __syncthreads();
    // phase 3: scatter-fill CSR in LDS
    for (int i = tid; i < Ee / 4; i += 1024) {
        int4 d = reinterpret_cast<const int4*>(dstp)[i];
        int4 s = reinterpret_cast<const int4*>(srcp)[i];
        if (d.x >= lo && d.x < hi) { int p = atomicAdd(&hist[d.x - lo], 1); if (p < QCAP) csr_l[p] = s.x; }
        if (d.y >= lo && d.y < hi) { int p = atomicAdd(&hist[d.y - lo], 1); if (p < QCAP) csr_l[p] = s.y; }
        if (d.z >= lo && d.z < hi) { int p = atomicAdd(&hist[d.z - lo], 1); if (p < QCAP) csr_l[p] = s.z; }
        if (d.w >= lo && d.w < hi) { int p = atomicAdd(&hist[d.w - lo], 1); if (p < QCAP) csr_l[p] = s.w; }
    }
    __syncthreads();
    // phase 4: coalesced write-out
    int total = ws[511];
    int* cg = csr + (size_t)gq * QCAP;
    for (int i = tid; i < total; i += 1024) cg[i] = csr_l[i];
}

// ---- K2: build padded ELL with folded weights, one thread per slot.
// slot 0: (n, dn*dn) self-loop; slots 1..31: (src, dis[src]*dn); pad: (n, 0).
__global__ void k_ell(const float* __restrict__ dis, const int* __restrict__ startA,
                      const int* __restrict__ cntA, const int* __restrict__ csr,
                      int2* __restrict__ ell) {
    int t = blockIdx.x * 256 + threadIdx.x;     // global slot id
    int slot = t & (PAD - 1);
    int gn = t >> 5;                            // 0 .. G*Nn-1
    int g = gn / Nn;
    int n = gn - g * Nn;
    float dn = dis[gn];
    int2 v;
    if (slot == 0) {
        v = make_int2(n, __float_as_int(dn * dn));
    } else {
        int e = slot - 1;
        int cnt = cntA[gn];
        if (e < cnt) {
            int s = csr[startA[gn] + e];
            v = make_int2(s, __float_as_int(dis[(size_t)g * Nn + s] * dn));
        } else {
            v = make_int2(n, 0);                // w = 0.0f
        }
    }
    ell[t] = v;
}

// ---- K3: fused per-node pipeline: aggX = ELL-agg(x) -> h1 = relu(aggX@W1+b1)
//          -> t2 = h1@W2.  32 nodes/block, XCD-pinned.
__global__ void __launch_bounds__(256)
k_mmf(const float* __restrict__ x, const int2* __restrict__ ell,
      const int* __restrict__ startA, const int* __restrict__ cntA,
      const int* __restrict__ csr, const float* __restrict__ dis,
      const float* __restrict__ W1, const float* __restrict__ b1,
      const float* __restrict__ W2, float* __restrict__ t2) {
    __shared__ float Ws1[512];
    __shared__ float bs[64];
    __shared__ float xs[256];          // aggX tile: 32 nodes x 8 features
    __shared__ float W2s[4096];
    __shared__ float h1s[32 * 65];
    int i = blockIdx.x;            // 0..7559; round-robin over 8 XCDs
    int xcd = i & 7;
    int j = i >> 3;                // 0..944
    int f15 = j / 63;              // 0..14
    int bx = j % 63;
    int g = xcd * 15 + f15;
    int tid = threadIdx.x;
    Ws1[tid]       = W1[tid];
    Ws1[tid + 256] = W1[tid + 256];
    if (tid < 64) bs[tid] = b1[tid];
#pragma unroll
    for (int k2 = 0; k2 < 16; ++k2) W2s[k2 * 256 + tid] = W2[k2 * 256 + tid];
    // phase 0: ELL aggregation of raw x (8-dim) into xs
    {
        int r0 = tid >> 3, f = tid & 7;       // node-in-block, feature
        int n = bx * 32 + r0;
        float v = 0.f;
        if (n < Nn) {
            size_t gn = (size_t)g * Nn + n;
            const float* xb = x + (size_t)g * Nn * 8;
            const int4* ep = reinterpret_cast<const int4*>(ell + gn * PAD);
            float acc = 0.f, acc2 = 0.f;
#pragma unroll
            for (int e = 0; e < 16; ++e) {
                int4 p = ep[e];
                acc  += xb[(size_t)p.x * 8 + f] * __int_as_float(p.y);
                acc2 += xb[(size_t)p.z * 8 + f] * __int_as_float(p.w);
            }
            int cnt = cntA[gn];
            if (cnt > 31) {                    // rare overflow (deg > 31)
                float dnl = dis[gn];
                int o0 = startA[gn];
                const float* dsg = dis + (size_t)g * Nn;
                for (int e = 31; e < cnt; ++e) {
                    int s = csr[o0 + e];
                    acc += xb[(size_t)s * 8 + f] * (dsg[s] * dnl);
                }
            }
            v = acc + acc2;
        }
        xs[tid] = 0.f;
        __syncthreads();
        xs[(tid >> 3) * 8 + (tid & 7)] = v;   // == xs[tid], kept explicit
    }
    __syncthreads();
    // phase 1: h1 = relu(aggX@W1 + b1) into LDS
    int f = tid & 63, rr = tid >> 6;
#pragma unroll
    for (int ii = 0; ii < 8; ++ii) {
        int r = rr + 4 * ii;
        float acc = bs[f];
#pragma unroll
        for (int k = 0; k < 8; ++k) acc += xs[r * 8 + k] * Ws1[k * 64 + f];
        h1s[r * 65 + f] = fmaxf(acc, 0.f);
    }
    __syncthreads();
    // phase 2: t2 = h1 @ W2, each thread: 1 node x 8 features
    int r2 = tid >> 3, fg = tid & 7;
    int n = bx * 32 + r2;
    if (n < Nn) {
        float4 a0 = {0.f, 0.f, 0.f, 0.f}, a1 = {0.f, 0.f, 0.f, 0.f};
        const float4* W24 = reinterpret_cast<const float4*>(W2s);
#pragma unroll 8
        for (int k = 0; k < 64; ++k) {
            float xv = h1s[r2 * 65 + k];
            float4 w0 = W24[k * 16 + fg * 2];
            float4 w1 = W24[k * 16 + fg * 2 + 1];
            a0.x += xv * w0.x; a0.y += xv * w0.y; a0.z += xv * w0.z; a0.w += xv * w0.w;
            a1.x += xv * w1.x; a1.y += xv * w1.y; a1.z += xv * w1.z; a1.w += xv * w1.w;
        }
        float4* op = reinterpret_cast<float4*>(t2 + ((size_t)g * Nn + n) * 64 + fg * 8);
        op[0] = a0; op[1] = a1;
    }
}

// ---- K4: h2 = relu(ELL-agg(t2)+b2) fused with mean-pool (h2 never stored).
// XCD-pinned swizzle; 4 nodes/block (one per wave); LDS reduce + 1 atomic wave.
__global__ void k_agg64p(const float* __restrict__ t2, const int2* __restrict__ ell,
                         const int* __restrict__ startA, const int* __restrict__ cntA,
                         const int* __restrict__ csr, const float* __restrict__ dis,
                         const float* __restrict__ bias, float* __restrict__ emb) {
    __shared__ float red[256];
    int i = blockIdx.x;            // 0..59999
    int xcd = i & 7;
    int chunk = i >> 3;            // 0..7499
    int ng = chunk % 500;
    int f15 = chunk / 500;         // 0..14
    int g = xcd * 15 + f15;
    int n = ng * 4 + (threadIdx.x >> 6);
    int f = threadIdx.x & 63;
    size_t gn = (size_t)g * Nn + n;
    const float* base = t2 + (size_t)g * Nn * 64;
    const int4* ep = reinterpret_cast<const int4*>(ell + gn * PAD);
    float acc = 0.f, acc2 = 0.f;
#pragma unroll
    for (int e = 0; e < 16; ++e) {
        int4 p = ep[e];
        acc  += base[(size_t)p.x * 64 + f] * __int_as_float(p.y);
        acc2 += base[(size_t)p.z * 64 + f] * __int_as_float(p.w);
    }
    int cnt = cntA[gn];
    if (cnt > 31) {                 // rare overflow; wave-uniform branch
        float dn = dis[gn];
        int o0 = startA[gn];
        const float* dsg = dis + (size_t)g * Nn;
        for (int e = 31; e < cnt; ++e) {
            int s = csr[o0 + e];
            acc += base[(size_t)s * 64 + f] * (dsg[s] * dn);
        }
    }
    float val = fmaxf(acc + acc2 + bias[f], 0.f);
    red[threadIdx.x] = val;
    __syncthreads();
    if (threadIdx.x < 64) {
        float s = red[threadIdx.x] + red[64 + threadIdx.x] +
                  red[128 + threadIdx.x] + red[192 + threadIdx.x];
        atomicAdd(&emb[g * 64 + threadIdx.x], s * (1.0f / Nn));
    }
}

// ---- K5: gi[g][384] = emb[g] @ W_ih^T + b_ih (parallel over frames)
__global__ void k_gi(const float* __restrict__ emb, const float* __restrict__ W_ih,
                     const float* __restrict__ b_ih, float* __restrict__ gi) {
    __shared__ float xs[64];
    int g = blockIdx.x;          // g = b*Tt + t
    int j = threadIdx.x;         // 0..383
    if (j < 64) xs[j] = emb[g * 64 + j];
    __syncthreads();
    float a0 = 0.f, a1 = 0.f, a2 = 0.f, a3 = 0.f;
    const float* wr = W_ih + j * 64;
#pragma unroll
    for (int k = 0; k < 16; ++k) {
        a0 += wr[4 * k + 0] * xs[4 * k + 0];
        a1 += wr[4 * k + 1] * xs[4 * k + 1];
        a2 += wr[4 * k + 2] * xs[4 * k + 2];
        a3 += wr[4 * k + 3] * xs[4 * k + 3];
    }
    gi[(size_t)g * 384 + j] = b_ih[j] + ((a0 + a1) + (a2 + a3));
}

// ---- K6: sequential GRU over T, one block per batch, W_hh in regs + final FC
__global__ void __launch_bounds__(768, 1)
k_gru_seq(const float* __restrict__ gi, const float* __restrict__ W_hh,
          const float* __restrict__ b_hh, const float* __restrict__ fc_w,
          const float* __restrict__ fc_b, float* __restrict__ out) {
    __shared__ float h[Fg];
    __shared__ float part[768];
    int b = blockIdx.x;                  // batch
    int tid = threadIdx.x;               // 0..767
    int row = tid >> 1;                  // gate-row 0..383
    int half = tid & 1;                  // which 64-slice of k
    float w[64];
    const float* wr = W_hh + (size_t)row * Fg + half * 64;
#pragma unroll
    for (int i = 0; i < 64; ++i) w[i] = wr[i];
    if (tid < Fg) h[tid] = 0.f;
    __syncthreads();
    for (int t = 0; t < Tt; ++t) {
        const float* hh = &h[half * 64];
        float a0 = 0.f, a1 = 0.f, a2 = 0.f, a3 = 0.f;
#pragma unroll
        for (int i = 0; i < 16; ++i) {
            a0 += w[4 * i + 0] * hh[4 * i + 0];
            a1 += w[4 * i + 1] * hh[4 * i + 1];
            a2 += w[4 * i + 2] * hh[4 * i + 2];
            a3 += w[4 * i + 3] * hh[4 * i + 3];
        }
        part[tid] = (a0 + a1) + (a2 + a3);
        __syncthreads();
        if (tid < Fg) {
            int j = tid;
            const float* gib = gi + ((size_t)b * Tt + t) * 384;
            float hr = b_hh[j]       + part[2 * j]           + part[2 * j + 1];
            float hz = b_hh[128 + j] + part[2 * (128 + j)]   + part[2 * (128 + j) + 1];
            float hn = b_hh[256 + j] + part[2 * (256 + j)]   + part[2 * (256 + j) + 1];
            float r  = 1.f / (1.f + expf(-(gib[j] + hr)));
            float z  = 1.f / (1.f + expf(-(gib[128 + j] + hz)));
            float nn = tanhf(gib[256 + j] + r * hn);
            h[j] = (1.f - z) * nn + z * h[j];
        }
        __syncthreads();
    }
    if (tid < 2) {
        float acc = fc_b[tid];
        for (int k = 0; k < Fg; ++k) acc += fc_w[tid * Fg + k] * h[k];
        out[b * 2 + tid] = acc;
    }
}

// ----------------------------------------------------------------- launcher
extern "C" void kernel_launch(void* const* d_in, const int* in_sizes, int n_in,
                              void* d_out, int out_size, void* d_ws, size_t ws_size,
                              hipStream_t stream) {
    const float* x     = (const float*)d_in[0];
    const int*   ei    = (const int*)  d_in[1];
    const float* W1    = (const float*)d_in[2];
    const float* b1    = (const float*)d_in[3];
    const float* W2    = (const float*)d_in[4];
    const float* b2    = (const float*)d_in[5];
    const float* W_ih  = (const float*)d_in[6];
    const float* W_hh  = (const float*)d_in[7];
    const float* b_ih  = (const float*)d_in[8];
    const float* b_hh  = (const float*)d_in[9];
    const float* fc_w  = (const float*)d_in[10];
    const float* fc_b  = (const float*)d_in[11];
    float* out = (float*)d_out;

    char* ws = (char*)d_ws;
    size_t off = 0;
    auto alloc = [&](size_t bytes) -> void* {
        void* p = ws + off;
        off = (off + bytes + 255) & ~(size_t)255;
        return p;
    };
    float* dis     = (float*)alloc((size_t)G * Nn * 4);
    int*   startA  = (int*)  alloc((size_t)G * Nn * 4);
    int*   cntA    = (int*)  alloc((size_t)G * Nn * 4);
    int*   csr     = (int*)  alloc((size_t)G * 4 * QCAP * 4);
    int2*  ell     = (int2*) alloc((size_t)G * Nn * PAD * 8);
    float* t2      = (float*)alloc((size_t)G * Nn * 64 * 4);
    float* emb     = (float*)alloc((size_t)G * 64 * 4);
    float* gi      = (float*)alloc((size_t)G * 384 * 4);
    (void)ws_size; (void)in_sizes; (void)n_in; (void)out_size;

    hipLaunchKernelGGL(k_csr,    dim3(G * 4), dim3(1024), 0, stream, ei, dis, startA, cntA, csr, emb);
    hipLaunchKernelGGL(k_ell,    dim3(G * Nn * PAD / 256), dim3(256), 0, stream, dis, startA, cntA, csr, ell);
    hipLaunchKernelGGL(k_mmf,    dim3(7560), dim3(256), 0, stream, x, ell, startA, cntA, csr, dis, W1, b1, W2, t2);
    hipLaunchKernelGGL(k_agg64p, dim3(60000), dim3(256), 0, stream, t2, ell, startA, cntA, csr, dis, b2, emb);
    hipLaunchKernelGGL(k_gi,     dim3(G), dim3(384), 0, stream, emb, W_ih, b_ih, gi);
    hipLaunchKernelGGL(k_gru_seq, dim3(Bb), dim3(768), 0, stream, gi, W_hh, b_hh, fc_w, fc_b, out);
}

// Round 7
// 437.719 us; speedup vs baseline: 1.1681x; 1.0344x over previous
//
#include <hip/hip_runtime.h>
#include <math.h>

// Problem constants (fixed by the reference)
#define G    120     // B*T frames
#define Nn   2000    // nodes per frame
#define Ee   32000   // edges per frame
#define Tt   30
#define Bb   4
#define Fg   128     // GRU hidden
#define QCAP 9216    // CSR capacity per (frame,quadrant); expected 8000, sigma 78
#define PAD  32      // ELL slots/node: slot0=self-loop, 1..31 edges, pad w=0

typedef unsigned short ushort8 __attribute__((ext_vector_type(8)));

static __device__ __forceinline__ unsigned short f2bf(float f) {
    unsigned u = __float_as_uint(f);
    u += 0x7fffu + ((u >> 16) & 1u);          // round-to-nearest-even
    return (unsigned short)(u >> 16);
}
static __device__ __forceinline__ float bf2f(unsigned short h) {
    return __uint_as_float(((unsigned)h) << 16);
}

// ---- K1: fused CSR build: histogram + scan + fill in LDS, coalesced write-out.
__global__ void __launch_bounds__(1024, 1)
k_csr(const int* __restrict__ ei, float* __restrict__ dis,
      int* __restrict__ startA, int* __restrict__ cntA,
      int* __restrict__ csr, float* __restrict__ emb) {
    __shared__ int hist[500];      // histogram, then cursor
    __shared__ int ws[512];        // scan workspace
    __shared__ int csr_l[QCAP];
    int gq = blockIdx.x;
    int g = gq >> 2, q = gq & 3;
    int lo = q * 500, hi = lo + 500;
    int tid = threadIdx.x;
    if (tid < 500) hist[tid] = 0;
    if (q == 0 && tid < 64) emb[g * 64 + tid] = 0.f;
    __syncthreads();
    const int* srcp = ei + (size_t)g * 2 * Ee;
    const int* dstp = srcp + Ee;
    for (int i = tid; i < Ee / 4; i += 1024) {
        int4 d = reinterpret_cast<const int4*>(dstp)[i];
        if (d.x >= lo && d.x < hi) atomicAdd(&hist[d.x - lo], 1);
        if (d.y >= lo && d.y < hi) atomicAdd(&hist[d.y - lo], 1);
        if (d.z >= lo && d.z < hi) atomicAdd(&hist[d.z - lo], 1);
        if (d.w >= lo && d.w < hi) atomicAdd(&hist[d.w - lo], 1);
    }
    __syncthreads();
    if (tid < 512) ws[tid] = (tid < 500) ? hist[tid] : 0;
    __syncthreads();
    for (int off = 1; off < 512; off <<= 1) {
        int v = 0;
        if (tid < 512 && tid >= off) v = ws[tid - off];
        __syncthreads();
        if (tid < 512) ws[tid] += v;
        __syncthreads();
    }
    if (tid < 500) {
        int cnt = hist[tid];
        int ex = ws[tid] - cnt;                    // exclusive prefix
        int n = lo + tid;
        startA[(size_t)g * Nn + n] = gq * QCAP + ex;
        cntA[(size_t)g * Nn + n]   = cnt;
        dis[(size_t)g * Nn + n]    = rsqrtf((float)cnt + 1.0f);
        hist[tid] = ex;                            // reuse as cursor
    }
    __syncthreads();
    for (int i = tid; i < Ee / 4; i += 1024) {
        int4 d = reinterpret_cast<const int4*>(dstp)[i];
        int4 s = reinterpret_cast<const int4*>(srcp)[i];
        if (d.x >= lo && d.x < hi) { int p = atomicAdd(&hist[d.x - lo], 1); if (p < QCAP) csr_l[p] = s.x; }
        if (d.y >= lo && d.y < hi) { int p = atomicAdd(&hist[d.y - lo], 1); if (p < QCAP) csr_l[p] = s.y; }
        if (d.z >= lo && d.z < hi) { int p = atomicAdd(&hist[d.z - lo], 1); if (p < QCAP) csr_l[p] = s.z; }
        if (d.w >= lo && d.w < hi) { int p = atomicAdd(&hist[d.w - lo], 1); if (p < QCAP) csr_l[p] = s.w; }
    }
    __syncthreads();
    int total = ws[511];
    int* cg = csr + (size_t)gq * QCAP;
    for (int i = tid; i < total; i += 1024) cg[i] = csr_l[i];
}

// ---- K2: build padded ELL with folded weights, one thread per slot.
// slot 0: (n, dn*dn) self-loop; slots 1..31: (src, dis[src]*dn); pad: (n, 0).
__global__ void k_ell(const float* __restrict__ dis, const int* __restrict__ startA,
                      const int* __restrict__ cntA, const int* __restrict__ csr,
                      int2* __restrict__ ell) {
    int t = blockIdx.x * 256 + threadIdx.x;     // global slot id
    int slot = t & (PAD - 1);
    int gn = t >> 5;                            // 0 .. G*Nn-1
    int g = gn / Nn;
    int n = gn - g * Nn;
    float dn = dis[gn];
    int2 v;
    if (slot == 0) {
        v = make_int2(n, __float_as_int(dn * dn));
    } else {
        int e = slot - 1;
        int cnt = cntA[gn];
        if (e < cnt) {
            int s = csr[startA[gn] + e];
            v = make_int2(s, __float_as_int(dis[(size_t)g * Nn + s] * dn));
        } else {
            v = make_int2(n, 0);                // w = 0.0f
        }
    }
    ell[t] = v;
}

// ---- K3: fused per-node pipeline: aggX = ELL-agg(x) -> h1 = relu(aggX@W1+b1)
//          -> t2 = h1@W2 stored as bf16.  32 nodes/block, XCD-pinned.
__global__ void __launch_bounds__(256)
k_mmf(const float* __restrict__ x, const int2* __restrict__ ell,
      const int* __restrict__ startA, const int* __restrict__ cntA,
      const int* __restrict__ csr, const float* __restrict__ dis,
      const float* __restrict__ W1, const float* __restrict__ b1,
      const float* __restrict__ W2, unsigned short* __restrict__ t2b) {
    __shared__ float Ws1[512];
    __shared__ float bs[64];
    __shared__ float xs[256];          // aggX tile: 32 nodes x 8 features
    __shared__ float W2s[4096];
    __shared__ float h1s[32 * 65];
    int i = blockIdx.x;            // 0..7559; round-robin over 8 XCDs
    int xcd = i & 7;
    int j = i >> 3;                // 0..944
    int f15 = j / 63;              // 0..14
    int bx = j % 63;
    int g = xcd * 15 + f15;
    int tid = threadIdx.x;
    Ws1[tid]       = W1[tid];
    Ws1[tid + 256] = W1[tid + 256];
    if (tid < 64) bs[tid] = b1[tid];
#pragma unroll
    for (int k2 = 0; k2 < 16; ++k2) W2s[k2 * 256 + tid] = W2[k2 * 256 + tid];
    // phase 0: trimmed ELL aggregation of raw x (8-dim) into xs
    {
        int r0 = tid >> 3, f = tid & 7;       // node-in-block, feature
        int n = bx * 32 + r0;
        float v = 0.f;
        if (n < Nn) {
            size_t gn = (size_t)g * Nn + n;
            const float* xb = x + (size_t)g * Nn * 8;
            const int4* ep = reinterpret_cast<const int4*>(ell + gn * PAD);
            int cnt = cntA[gn];
            int ncap = min(cnt + 1, PAD);
            int nint4 = (ncap + 1) >> 1;
            float acc = 0.f, acc2 = 0.f;
#pragma unroll 4
            for (int e = 0; e < nint4; ++e) {
                int4 p = ep[e];
                acc  += xb[(size_t)p.x * 8 + f] * __int_as_float(p.y);
                acc2 += xb[(size_t)p.z * 8 + f] * __int_as_float(p.w);
            }
            if (cnt > PAD - 1) {               // rare overflow (deg > 31)
                float dnl = dis[gn];
                int o0 = startA[gn];
                const float* dsg = dis + (size_t)g * Nn;
                for (int e = PAD - 1; e < cnt; ++e) {
                    int s = csr[o0 + e];
                    acc += xb[(size_t)s * 8 + f] * (dsg[s] * dnl);
                }
            }
            v = acc + acc2;
        }
        xs[tid] = v;                           // tid == r0*8+f
    }
    __syncthreads();
    // phase 1: h1 = relu(aggX@W1 + b1) into LDS
    int f = tid & 63, rr = tid >> 6;
#pragma unroll
    for (int ii = 0; ii < 8; ++ii) {
        int r = rr + 4 * ii;
        float acc = bs[f];
#pragma unroll
        for (int k = 0; k < 8; ++k) acc += xs[r * 8 + k] * Ws1[k * 64 + f];
        h1s[r * 65 + f] = fmaxf(acc, 0.f);
    }
    __syncthreads();
    // phase 2: t2 = h1 @ W2 (bf16 out), each thread: 1 node x 8 features
    int r2 = tid >> 3, fg = tid & 7;
    int n = bx * 32 + r2;
    if (n < Nn) {
        float4 a0 = {0.f, 0.f, 0.f, 0.f}, a1 = {0.f, 0.f, 0.f, 0.f};
        const float4* W24 = reinterpret_cast<const float4*>(W2s);
#pragma unroll 8
        for (int k = 0; k < 64; ++k) {
            float xv = h1s[r2 * 65 + k];
            float4 w0 = W24[k * 16 + fg * 2];
            float4 w1 = W24[k * 16 + fg * 2 + 1];
            a0.x += xv * w0.x; a0.y += xv * w0.y; a0.z += xv * w0.z; a0.w += xv * w0.w;
            a1.x += xv * w1.x; a1.y += xv * w1.y; a1.z += xv * w1.z; a1.w += xv * w1.w;
        }
        ushort8 ov;
        ov[0] = f2bf(a0.x); ov[1] = f2bf(a0.y); ov[2] = f2bf(a0.z); ov[3] = f2bf(a0.w);
        ov[4] = f2bf(a1.x); ov[5] = f2bf(a1.y); ov[6] = f2bf(a1.z); ov[7] = f2bf(a1.w);
        *reinterpret_cast<ushort8*>(t2b + ((size_t)g * Nn + n) * 64 + fg * 8) = ov;
    }
}

// ---- K4: h2 = relu(trimmed-ELL-agg(t2 bf16)+b2) fused with mean-pool.
// XCD-pinned swizzle; 4 nodes/block (one per wave); LDS reduce + 1 atomic wave.
__global__ void k_agg64p(const unsigned short* __restrict__ t2b, const int2* __restrict__ ell,
                         const int* __restrict__ startA, const int* __restrict__ cntA,
                         const int* __restrict__ csr, const float* __restrict__ dis,
                         const float* __restrict__ bias, float* __restrict__ emb) {
    __shared__ float red[256];
    int i = blockIdx.x;            // 0..59999
    int xcd = i & 7;
    int chunk = i >> 3;            // 0..7499
    int ng = chunk % 500;
    int f15 = chunk / 500;         // 0..14
    int g = xcd * 15 + f15;
    int n = ng * 4 + (threadIdx.x >> 6);
    int f = threadIdx.x & 63;
    size_t gn = (size_t)g * Nn + n;
    const unsigned short* base = t2b + (size_t)g * Nn * 64;
    const int4* ep = reinterpret_cast<const int4*>(ell + gn * PAD);
    int cnt = cntA[gn];                 // wave-uniform (one node per wave)
    int ncap = min(cnt + 1, PAD);
    int nint4 = (ncap + 1) >> 1;
    float acc = 0.f, acc2 = 0.f;
#pragma unroll 4
    for (int e = 0; e < nint4; ++e) {
        int4 p = ep[e];
        acc  += bf2f(base[(size_t)p.x * 64 + f]) * __int_as_float(p.y);
        acc2 += bf2f(base[(size_t)p.z * 64 + f]) * __int_as_float(p.w);
    }
    if (cnt > PAD - 1) {                // rare overflow; wave-uniform branch
        float dn = dis[gn];
        int o0 = startA[gn];
        const float* dsg = dis + (size_t)g * Nn;
        for (int e = PAD - 1; e < cnt; ++e) {
            int s = csr[o0 + e];
            acc += bf2f(base[(size_t)s * 64 + f]) * (dsg[s] * dn);
        }
    }
    float val = fmaxf(acc + acc2 + bias[f], 0.f);
    red[threadIdx.x] = val;
    __syncthreads();
    if (threadIdx.x < 64) {
        float s = red[threadIdx.x] + red[64 + threadIdx.x] +
                  red[128 + threadIdx.x] + red[192 + threadIdx.x];
        atomicAdd(&emb[g * 64 + threadIdx.x], s * (1.0f / Nn));
    }
}

// ---- K5: gi[g][384] = emb[g] @ W_ih^T + b_ih (parallel over frames)
__global__ void k_gi(const float* __restrict__ emb, const float* __restrict__ W_ih,
                     const float* __restrict__ b_ih, float* __restrict__ gi) {
    __shared__ float xs[64];
    int g = blockIdx.x;          // g = b*Tt + t
    int j = threadIdx.x;         // 0..383
    if (j < 64) xs[j] = emb[g * 64 + j];
    __syncthreads();
    float a0 = 0.f, a1 = 0.f, a2 = 0.f, a3 = 0.f;
    const float* wr = W_ih + j * 64;
#pragma unroll
    for (int k = 0; k < 16; ++k) {
        a0 += wr[4 * k + 0] * xs[4 * k + 0];
        a1 += wr[4 * k + 1] * xs[4 * k + 1];
        a2 += wr[4 * k + 2] * xs[4 * k + 2];
        a3 += wr[4 * k + 3] * xs[4 * k + 3];
    }
    gi[(size_t)g * 384 + j] = b_ih[j] + ((a0 + a1) + (a2 + a3));
}

// ---- K6: sequential GRU over T, one block per batch, W_hh in regs + final FC
__global__ void __launch_bounds__(768, 1)
k_gru_seq(const float* __restrict__ gi, const float* __restrict__ W_hh,
          const float* __restrict__ b_hh, const float* __restrict__ fc_w,
          const float* __restrict__ fc_b, float* __restrict__ out) {
    __shared__ float h[Fg];
    __shared__ float part[768];
    int b = blockIdx.x;                  // batch
    int tid = threadIdx.x;               // 0..767
    int row = tid >> 1;                  // gate-row 0..383
    int half = tid & 1;                  // which 64-slice of k
    float w[64];
    const float* wr = W_hh + (size_t)row * Fg + half * 64;
#pragma unroll
    for (int i = 0; i < 64; ++i) w[i] = wr[i];
    if (tid < Fg) h[tid] = 0.f;
    __syncthreads();
    for (int t = 0; t < Tt; ++t) {
        const float* hh = &h[half * 64];
        float a0 = 0.f, a1 = 0.f, a2 = 0.f, a3 = 0.f;
#pragma unroll
        for (int i = 0; i < 16; ++i) {
            a0 += w[4 * i + 0] * hh[4 * i + 0];
            a1 += w[4 * i + 1] * hh[4 * i + 1];
            a2 += w[4 * i + 2] * hh[4 * i + 2];
            a3 += w[4 * i + 3] * hh[4 * i + 3];
        }
        part[tid] = (a0 + a1) + (a2 + a3);
        __syncthreads();
        if (tid < Fg) {
            int j = tid;
            const float* gib = gi + ((size_t)b * Tt + t) * 384;
            float hr = b_hh[j]       + part[2 * j]           + part[2 * j + 1];
            float hz = b_hh[128 + j] + part[2 * (128 + j)]   + part[2 * (128 + j) + 1];
            float hn = b_hh[256 + j] + part[2 * (256 + j)]   + part[2 * (256 + j) + 1];
            float r  = 1.f / (1.f + expf(-(gib[j] + hr)));
            float z  = 1.f / (1.f + expf(-(gib[128 + j] + hz)));
            float nn = tanhf(gib[256 + j] + r * hn);
            h[j] = (1.f - z) * nn + z * h[j];
        }
        __syncthreads();
    }
    if (tid < 2) {
        float acc = fc_b[tid];
        for (int k = 0; k < Fg; ++k) acc += fc_w[tid * Fg + k] * h[k];
        out[b * 2 + tid] = acc;
    }
}

// ----------------------------------------------------------------- launcher
extern "C" void kernel_launch(void* const* d_in, const int* in_sizes, int n_in,
                              void* d_out, int out_size, void* d_ws, size_t ws_size,
                              hipStream_t stream) {
    const float* x     = (const float*)d_in[0];
    const int*   ei    = (const int*)  d_in[1];
    const float* W1    = (const float*)d_in[2];
    const float* b1    = (const float*)d_in[3];
    const float* W2    = (const float*)d_in[4];
    const float* b2    = (const float*)d_in[5];
    const float* W_ih  = (const float*)d_in[6];
    const float* W_hh  = (const float*)d_in[7];
    const float* b_ih  = (const float*)d_in[8];
    const float* b_hh  = (const float*)d_in[9];
    const float* fc_w  = (const float*)d_in[10];
    const float* fc_b  = (const float*)d_in[11];
    float* out = (float*)d_out;

    char* ws = (char*)d_ws;
    size_t off = 0;
    auto alloc = [&](size_t bytes) -> void* {
        void* p = ws + off;
        off = (off + bytes + 255) & ~(size_t)255;
        return p;
    };
    float* dis     = (float*)alloc((size_t)G * Nn * 4);
    int*   startA  = (int*)  alloc((size_t)G * Nn * 4);
    int*   cntA    = (int*)  alloc((size_t)G * Nn * 4);
    int*   csr     = (int*)  alloc((size_t)G * 4 * QCAP * 4);
    int2*  ell     = (int2*) alloc((size_t)G * Nn * PAD * 8);
    unsigned short* t2b = (unsigned short*)alloc((size_t)G * Nn * 64 * 2);
    float* emb     = (float*)alloc((size_t)G * 64 * 4);
    float* gi      = (float*)alloc((size_t)G * 384 * 4);
    (void)ws_size; (void)in_sizes; (void)n_in; (void)out_size;

    hipLaunchKernelGGL(k_csr,    dim3(G * 4), dim3(1024), 0, stream, ei, dis, startA, cntA, csr, emb);
    hipLaunchKernelGGL(k_ell,    dim3(G * Nn * PAD / 256), dim3(256), 0, stream, dis, startA, cntA, csr, ell);
    hipLaunchKernelGGL(k_mmf,    dim3(7560), dim3(256), 0, stream, x, ell, startA, cntA, csr, dis, W1, b1, W2, t2b);
    hipLaunchKernelGGL(k_agg64p, dim3(60000), dim3(256), 0, stream, t2b, ell, startA, cntA, csr, dis, b2, emb);
    hipLaunchKernelGGL(k_gi,     dim3(G), dim3(384), 0, stream, emb, W_ih, b_ih, gi);
    hipLaunchKernelGGL(k_gru_seq, dim3(Bb), dim3(768), 0, stream, gi, W_hh, b_hh, fc_w, fc_b, out);
}